// Round 2
// baseline (3225.925 us; speedup 1.0000x reference)
//
#include <hip/hip_runtime.h>
#include <hip/hip_bf16.h>
#include <stdint.h>

typedef __bf16 bf16_t;
typedef bf16_t bf16x8 __attribute__((ext_vector_type(8)));
typedef float f32x4 __attribute__((ext_vector_type(4)));

#define N_NODES 10000
#define N_EDGES 160000
#define IN_DIM 128
#define HID 512
#define LN_EPS 1e-5f

// ---------------- small utility kernels ----------------

__global__ void k_cast(const float* __restrict__ s, bf16_t* __restrict__ d, int n) {
  int i = blockIdx.x * 256 + threadIdx.x;
  if (i < n) d[i] = (bf16_t)s[i];
}

// dst[n*K + k] = (bf16)src[k*N + n];  K = 1<<kbits (contraction dim)
__global__ void k_tcast(const float* __restrict__ src, bf16_t* __restrict__ dst,
                        int kbits, int N, int total) {
  int i = blockIdx.x * 256 + threadIdx.x;
  if (i >= total) return;
  int K = 1 << kbits;
  int n = i >> kbits;
  int k = i & (K - 1);
  dst[i] = (bf16_t)src[(size_t)k * N + n];
}

__global__ void k_deg_init(float* deg) {
  int i = blockIdx.x * 256 + threadIdx.x;
  if (i < N_NODES) deg[i] = 1.0f;  // self-loop
}
__global__ void k_deg_count(const int* __restrict__ col, float* deg) {
  int e = blockIdx.x * 256 + threadIdx.x;
  if (e < N_EDGES) atomicAdd(&deg[col[e]], 1.0f);
}
__global__ void k_dis(const float* __restrict__ deg, float* __restrict__ dis) {
  int i = blockIdx.x * 256 + threadIdx.x;
  if (i < N_NODES) dis[i] = rsqrtf(deg[i]);  // deg >= 1 always
}

// Agg[n][d] = dis[n]^2 * T[n][d] + bias[d]   (self-loop term + bias)
__global__ void k_agg_init(const float* __restrict__ T, const float* __restrict__ dis,
                           const float* __restrict__ bias, float* __restrict__ Agg) {
  int i = blockIdx.x * 256 + threadIdx.x;
  if (i >= N_NODES * HID) return;
  int n = i >> 9, d = i & 511;
  float w = dis[n];
  Agg[i] = w * w * T[i] + bias[d];
}

// one block per edge: Agg[col] += dis[row]*dis[col] * T[row]
__global__ __launch_bounds__(256) void k_agg_edges(
    const int* __restrict__ ei, const float* __restrict__ dis,
    const float* __restrict__ T, float* __restrict__ Agg) {
  int e = blockIdx.x;
  int s = ei[e];
  int t = ei[N_EDGES + e];
  float w = dis[s] * dis[t];
  const float* Ts = T + (size_t)s * HID;
  float* Ag = Agg + (size_t)t * HID;
  int d = threadIdx.x;
  atomicAdd(&Ag[d], w * Ts[d]);
  atomicAdd(&Ag[d + 256], w * Ts[d + 256]);
}

// one block per row. relu_first=1: y=LN(relu(x)); relu_first=0: y=relu(LN(x))
// input: fp32 inF. output: bf16 to outB if non-null, else fp32 to outF.
__global__ __launch_bounds__(256) void k_relu_ln(
    const float* __restrict__ inF, bf16_t* __restrict__ outB,
    float* __restrict__ outF, const float* __restrict__ g,
    const float* __restrict__ b, int D, int relu_first) {
  int row = blockIdx.x, tid = threadIdx.x;
  size_t base = (size_t)row * D;
  int per = D >> 8;  // 2 or 4
  float v[4];
  float s1 = 0.f, s2 = 0.f;
#pragma unroll
  for (int i = 0; i < 4; ++i) {
    if (i < per) {
      int d = tid + (i << 8);
      float x = inF[base + d];
      if (relu_first) x = fmaxf(x, 0.f);
      v[i] = x;
      s1 += x;
      s2 += x * x;
    }
  }
#pragma unroll
  for (int off = 32; off > 0; off >>= 1) {
    s1 += __shfl_xor(s1, off);
    s2 += __shfl_xor(s2, off);
  }
  __shared__ float ls1[4], ls2[4];
  int w = tid >> 6;
  if ((tid & 63) == 0) { ls1[w] = s1; ls2[w] = s2; }
  __syncthreads();
  float t1 = ls1[0] + ls1[1] + ls1[2] + ls1[3];
  float t2 = ls2[0] + ls2[1] + ls2[2] + ls2[3];
  float invD = 1.0f / (float)D;
  float mean = t1 * invD;
  float var = t2 * invD - mean * mean;
  float inv = rsqrtf(var + LN_EPS);
#pragma unroll
  for (int i = 0; i < 4; ++i) {
    if (i < per) {
      int d = tid + (i << 8);
      float y = (v[i] - mean) * inv * g[d] + b[d];
      if (!relu_first) y = fmaxf(y, 0.f);
      if (outB) outB[base + d] = (bf16_t)y;
      else outF[base + d] = y;
    }
  }
}

// ---------------- GEMM: C[M x N] = A[M x K] @ B[K x N] (+bias) ----------------
// Bt is B transposed: [N x K]. gather=1: A row m = concat(Hn[src[m]], Hn[dst[m]]).
// Output: fp32 to Cf.
#define BM 128
#define BN 128
#define BK 32
#define LDK 40  // 32 + 8 bf16 pad (keeps 16B alignment, breaks bank aliasing)

__global__ __launch_bounds__(256) void k_gemm(
    const bf16_t* __restrict__ A, const bf16_t* __restrict__ Hn,
    const int* __restrict__ srcI, const int* __restrict__ dstI,
    const bf16_t* __restrict__ Bt, const float* __restrict__ bias,
    float* __restrict__ Cf, int M, int N, int K, int gather) {
  __shared__ __align__(16) bf16_t sA[BM][LDK];
  __shared__ __align__(16) bf16_t sB[BN][LDK];
  __shared__ int sSrc[BM], sDst[BM];

  int tid = threadIdx.x;
  int row0 = blockIdx.y * BM, col0 = blockIdx.x * BN;

  if (gather) {
    if (tid < BM) {
      sSrc[tid] = srcI[row0 + tid];
      sDst[tid] = dstI[row0 + tid];
    }
    __syncthreads();
  }

  int w = tid >> 6, lane = tid & 63;
  int quad = lane >> 4, l15 = lane & 15;
  int wr = (w >> 1) << 6, wc = (w & 1) << 6;

  f32x4 acc[4][4] = {};

  for (int k0 = 0; k0 < K; k0 += BK) {
    // stage A and B tiles: 128 rows x 32 bf16, 16B per thread-chunk
#pragma unroll
    for (int h = 0; h < 2; ++h) {
      int c = tid + (h << 8);
      int r = c >> 2, seg = c & 3;
      int kk = k0 + (seg << 3);
      const bf16_t* pa;
      if (gather) {
        int node = (kk < HID) ? sSrc[r] : sDst[r];
        pa = Hn + (size_t)node * HID + (kk & (HID - 1));
      } else {
        int gr = row0 + r;
        if (gr >= M) gr = M - 1;  // clamp; rows >= M never stored
        pa = A + (size_t)gr * K + kk;
      }
      *(bf16x8*)&sA[r][seg << 3] = *(const bf16x8*)pa;
      const bf16_t* pb = Bt + (size_t)(col0 + r) * K + kk;
      *(bf16x8*)&sB[r][seg << 3] = *(const bf16x8*)pb;
    }
    __syncthreads();

    bf16x8 af[4], bfr[4];
#pragma unroll
    for (int i = 0; i < 4; ++i)
      af[i] = *(const bf16x8*)&sA[wr + (i << 4) + l15][quad << 3];
#pragma unroll
    for (int j = 0; j < 4; ++j)
      bfr[j] = *(const bf16x8*)&sB[wc + (j << 4) + l15][quad << 3];
#pragma unroll
    for (int i = 0; i < 4; ++i)
#pragma unroll
      for (int j = 0; j < 4; ++j)
        acc[i][j] = __builtin_amdgcn_mfma_f32_16x16x32_bf16(af[i], bfr[j], acc[i][j], 0, 0, 0);
    __syncthreads();
  }

  // epilogue: C/D layout col=lane&15, row=quad*4+reg (verified m89/m91)
#pragma unroll
  for (int i = 0; i < 4; ++i) {
    int r0 = row0 + wr + (i << 4) + (quad << 2);
#pragma unroll
    for (int j = 0; j < 4; ++j) {
      int gc = col0 + wc + (j << 4) + l15;
      float bb = bias ? bias[gc] : 0.0f;
#pragma unroll
      for (int r2 = 0; r2 < 4; ++r2) {
        int gr = r0 + r2;
        if (gr < M) Cf[(size_t)gr * N + gc] = acc[i][j][r2] + bb;
      }
    }
  }
}

// bf16 cast helper for LN-output -> next GEMM input is handled inside k_relu_ln.

// out[e] = dot(z1[e,:512], mw2) + mb2 — one wave per edge, all fp32
__global__ __launch_bounds__(256) void k_gemv_out(
    const float* __restrict__ z1, const float* __restrict__ mw2,
    const float* __restrict__ mb2, float* __restrict__ out, int E) {
  int w = threadIdx.x >> 6, lane = threadIdx.x & 63;
  int e = blockIdx.x * 4 + w;
  if (e >= E) return;
  const float* zp = z1 + (size_t)e * HID + (lane << 3);
  float s = 0.f;
#pragma unroll
  for (int i = 0; i < 8; ++i) s += zp[i] * mw2[(lane << 3) + i];
#pragma unroll
  for (int off = 32; off > 0; off >>= 1) s += __shfl_xor(s, off);
  if (lane == 0) out[e] = s + mb2[0];
}

// ---------------- host launch ----------------

extern "C" void kernel_launch(void* const* d_in, const int* in_sizes, int n_in,
                              void* d_out, int out_size, void* d_ws, size_t ws_size,
                              hipStream_t stream) {
  const float* x = (const float*)d_in[0];
  const int* ei = (const int*)d_in[1];  // int64 in reference -> int32 from harness
  const float* w0 = (const float*)d_in[2];
  const float* b0 = (const float*)d_in[3];
  const float* wsL = (const float*)d_in[4];
  const float* bsL = (const float*)d_in[5];
  const float* ln_g = (const float*)d_in[6];
  const float* ln_b = (const float*)d_in[7];
  const float* mw0 = (const float*)d_in[8];
  const float* mb0 = (const float*)d_in[9];
  const float* mg0 = (const float*)d_in[10];
  const float* mbt0 = (const float*)d_in[11];
  const float* mw1 = (const float*)d_in[12];
  const float* mb1 = (const float*)d_in[13];
  const float* mg1 = (const float*)d_in[14];
  const float* mbt1 = (const float*)d_in[15];
  const float* mw2 = (const float*)d_in[16];
  const float* mb2 = (const float*)d_in[17];
  float* out = (float*)d_out;

  char* p = (char*)d_ws;
  auto alloc = [&](size_t bytes) -> void* {
    void* r = (void*)p;
    p += (bytes + 255) & ~(size_t)255;
    return r;
  };
  // persistent-through-MLP allocations first
  float* deg = (float*)alloc((size_t)N_NODES * 4);
  float* dis = (float*)alloc((size_t)N_NODES * 4);
  bf16_t* xb = (bf16_t*)alloc((size_t)N_NODES * IN_DIM * 2);
  bf16_t* hb0 = (bf16_t*)alloc((size_t)N_NODES * HID * 2);
  bf16_t* hb1 = (bf16_t*)alloc((size_t)N_NODES * HID * 2);
  bf16_t* w0t = (bf16_t*)alloc((size_t)HID * IN_DIM * 2);
  bf16_t* wst = (bf16_t*)alloc((size_t)3 * HID * HID * 2);
  bf16_t* mw0t = (bf16_t*)alloc((size_t)1024 * 1024 * 2);
  bf16_t* mw1t = (bf16_t*)alloc((size_t)512 * 1024 * 2);
  size_t fixed = (size_t)(p - (char*)d_ws);

  // GCN-phase buffers; dead once the MLP starts, so the MLP chunk buffers
  // alias this same region.
  char* pool = p;
  float* T = (float*)alloc((size_t)N_NODES * HID * 4);
  float* Agg = (float*)alloc((size_t)N_NODES * HID * 4);

  // edge-chunk size for the MLP buffers (divides 160000, multiple of 128);
  // per-edge bytes: z0f 4096 + z0b 2048 + z1f 2048 = 8192
  int CE = 3200;
  const int ce_opts[3] = {32000, 16000, 6400};
  for (int i = 0; i < 3; ++i) {
    size_t need = fixed + (size_t)ce_opts[i] * 8192 + 1024;
    if (need <= ws_size) { CE = ce_opts[i]; break; }
  }
  char* q = pool;
  auto alloc2 = [&](size_t bytes) -> void* {
    void* r = (void*)q;
    q += (bytes + 255) & ~(size_t)255;
    return r;
  };
  float* z0f = (float*)alloc2((size_t)CE * 1024 * 4);
  bf16_t* z0b = (bf16_t*)alloc2((size_t)CE * 1024 * 2);
  float* z1f = (float*)alloc2((size_t)CE * 512 * 4);

  // ---- precompute: bf16 casts + transposed weights, degree norm ----
  k_cast<<<(N_NODES * IN_DIM + 255) / 256, 256, 0, stream>>>(x, xb, N_NODES * IN_DIM);
  k_tcast<<<(IN_DIM * HID + 255) / 256, 256, 0, stream>>>(w0, w0t, 7, HID, IN_DIM * HID);
  for (int i = 0; i < 3; ++i)
    k_tcast<<<(HID * HID + 255) / 256, 256, 0, stream>>>(
        wsL + (size_t)i * HID * HID, wst + (size_t)i * HID * HID, 9, HID, HID * HID);
  k_tcast<<<(1024 * 1024 + 255) / 256, 256, 0, stream>>>(mw0, mw0t, 10, 1024, 1024 * 1024);
  k_tcast<<<(1024 * 512 + 255) / 256, 256, 0, stream>>>(mw1, mw1t, 10, 512, 1024 * 512);

  k_deg_init<<<(N_NODES + 255) / 256, 256, 0, stream>>>(deg);
  k_deg_count<<<(N_EDGES + 255) / 256, 256, 0, stream>>>(ei + N_EDGES, deg);
  k_dis<<<(N_NODES + 255) / 256, 256, 0, stream>>>(deg, dis);

  // ---- 4 GCN layers ----
  bf16_t* hbufs[2] = {hb0, hb1};
  for (int L = 0; L < 4; ++L) {
    const bf16_t* Ain = (L == 0) ? xb : hbufs[(L + 1) & 1];
    int K = (L == 0) ? IN_DIM : HID;
    const bf16_t* Bt = (L == 0) ? w0t : wst + (size_t)(L - 1) * HID * HID;
    dim3 grid(HID / BN, (N_NODES + BM - 1) / BM);
    k_gemm<<<grid, 256, 0, stream>>>(Ain, nullptr, nullptr, nullptr, Bt, nullptr,
                                     T, N_NODES, HID, K, 0);
    const float* bias = (L == 0) ? b0 : bsL + (size_t)(L - 1) * HID;
    k_agg_init<<<(N_NODES * HID + 255) / 256, 256, 0, stream>>>(T, dis, bias, Agg);
    k_agg_edges<<<N_EDGES, 256, 0, stream>>>(ei, dis, T, Agg);
    k_relu_ln<<<N_NODES, 256, 0, stream>>>(Agg, hbufs[L & 1], nullptr,
                                           ln_g + (size_t)L * HID,
                                           ln_b + (size_t)L * HID, HID, 1);
  }
  bf16_t* hfin = hbufs[1];  // layer 3 writes hbufs[1]

  // ---- edge MLP, chunked ----
  int nchunks = N_EDGES / CE;
  for (int c = 0; c < nchunks; ++c) {
    int e0 = c * CE;
    const int* srcI = ei + e0;
    const int* dstI = ei + N_EDGES + e0;
    dim3 g1(1024 / BN, CE / BM);
    k_gemm<<<g1, 256, 0, stream>>>(nullptr, hfin, srcI, dstI, mw0t, mb0,
                                   z0f, CE, 1024, 1024, 1);
    k_relu_ln<<<CE, 256, 0, stream>>>(z0f, z0b, nullptr, mg0, mbt0, 1024, 0);
    dim3 g2(HID / BN, CE / BM);
    k_gemm<<<g2, 256, 0, stream>>>(z0b, nullptr, nullptr, nullptr, mw1t, mb1,
                                   z1f, CE, HID, 1024, 0);
    k_relu_ln<<<CE, 256, 0, stream>>>(z1f, nullptr, z1f, mg1, mbt1, HID, 0);
    k_gemv_out<<<CE / 4, 256, 0, stream>>>(z1f, mw2, mb2, out + e0, CE);
  }
  (void)in_sizes; (void)n_in; (void)out_size;
}

// Round 3
// 2337.417 us; speedup vs baseline: 1.3801x; 1.3801x over previous
//
#include <hip/hip_runtime.h>
#include <hip/hip_bf16.h>
#include <stdint.h>

typedef __bf16 bf16_t;
typedef bf16_t bf16x8 __attribute__((ext_vector_type(8)));
typedef float f32x4 __attribute__((ext_vector_type(4)));

#define N_NODES 10000
#define N_EDGES 160000
#define IN_DIM 128
#define HID 512
#define LN_EPS 1e-5f

// ---------------- small utility kernels ----------------

__global__ void k_cast(const float* __restrict__ s, bf16_t* __restrict__ d, int n) {
  int i = blockIdx.x * 256 + threadIdx.x;
  if (i < n) d[i] = (bf16_t)s[i];
}

// dst[n*K + k] = (bf16)src[k*N + n];  K = 1<<kbits (contraction dim)
__global__ void k_tcast(const float* __restrict__ src, bf16_t* __restrict__ dst,
                        int kbits, int N, int total) {
  int i = blockIdx.x * 256 + threadIdx.x;
  if (i >= total) return;
  int K = 1 << kbits;
  int n = i >> kbits;
  int k = i & (K - 1);
  dst[i] = (bf16_t)src[(size_t)k * N + n];
}

__global__ void k_deg_init(float* deg) {
  int i = blockIdx.x * 256 + threadIdx.x;
  if (i < N_NODES) deg[i] = 1.0f;  // self-loop
}
__global__ void k_deg_count(const int* __restrict__ col, float* deg) {
  int e = blockIdx.x * 256 + threadIdx.x;
  if (e < N_EDGES) atomicAdd(&deg[col[e]], 1.0f);
}
__global__ void k_dis(const float* __restrict__ deg, float* __restrict__ dis) {
  int i = blockIdx.x * 256 + threadIdx.x;
  if (i < N_NODES) dis[i] = rsqrtf(deg[i]);  // deg >= 1 always
}

// ---------------- CSR build (edges sorted by target) ----------------

__global__ void k_zero2(int* a, int* b) {
  int i = blockIdx.x * 256 + threadIdx.x;
  if (i < N_NODES) { a[i] = 0; b[i] = 0; }
}
__global__ void k_cnt(const int* __restrict__ col, int* cnt) {
  int e = blockIdx.x * 256 + threadIdx.x;
  if (e < N_EDGES) atomicAdd(&cnt[col[e]], 1);
}
// single-block exclusive scan: rowptr[0..N_NODES]
__global__ __launch_bounds__(256) void k_scan(const int* __restrict__ cnt,
                                              int* __restrict__ rowptr) {
  __shared__ int part[256];
  __shared__ int pref[257];
  int tid = threadIdx.x;
  const int CH = 40;  // 256*40 >= 10001
  int s = 0;
  for (int i = 0; i < CH; ++i) {
    int idx = tid * CH + i;
    if (idx < N_NODES) s += cnt[idx];
  }
  part[tid] = s;
  __syncthreads();
  if (tid == 0) {
    int a = 0;
    for (int i = 0; i < 256; ++i) { pref[i] = a; a += part[i]; }
    pref[256] = a;
  }
  __syncthreads();
  int a = pref[tid];
  for (int i = 0; i < CH; ++i) {
    int idx = tid * CH + i;
    if (idx < N_NODES) {
      rowptr[idx] = a;
      a += cnt[idx];
    } else if (idx == N_NODES) {
      rowptr[idx] = a;  // == total edges for the thread whose chunk starts at N_NODES
    }
  }
}
__global__ void k_fill(const int* __restrict__ ei, const float* __restrict__ dis,
                       const int* __restrict__ rowptr, int* __restrict__ cursor,
                       int* __restrict__ esrc, float* __restrict__ ew) {
  int e = blockIdx.x * 256 + threadIdx.x;
  if (e >= N_EDGES) return;
  int s = ei[e];
  int t = ei[N_EDGES + e];
  int pos = atomicAdd(&cursor[t], 1);
  int o = rowptr[t] + pos;
  esrc[o] = s;
  ew[o] = dis[s] * dis[t];
}

// ---------------- fused aggregation + ReLU + LayerNorm ----------------
// one wave per node: acc = dis[n]^2*T[n] + bias + sum_e w_e * T[src_e];
// out = LN(relu(acc)) in bf16. 8 fp32 per lane (512 dims / 64 lanes).
__global__ __launch_bounds__(256) void k_agg_ln(
    const float* __restrict__ T, const int* __restrict__ rowptr,
    const int* __restrict__ esrc, const float* __restrict__ ew,
    const float* __restrict__ dis, const float* __restrict__ bias,
    const float* __restrict__ g, const float* __restrict__ b,
    bf16_t* __restrict__ out) {
  int w = threadIdx.x >> 6, lane = threadIdx.x & 63;
  int node = blockIdx.x * 4 + w;
  if (node >= N_NODES) return;
  int d0 = lane << 3;  // 8 dims per lane
  float dw = dis[node];
  dw *= dw;
  f32x4 a0, a1;
  {
    const f32x4* Tn = (const f32x4*)(T + (size_t)node * HID + d0);
    const f32x4* bi = (const f32x4*)(bias + d0);
    a0 = dw * Tn[0] + bi[0];
    a1 = dw * Tn[1] + bi[1];
  }
  int e0 = rowptr[node], e1 = rowptr[node + 1];
  for (int e = e0; e < e1; ++e) {
    int s = esrc[e];
    float wgt = ew[e];
    const f32x4* Ts = (const f32x4*)(T + (size_t)s * HID + d0);
    f32x4 t0 = Ts[0], t1 = Ts[1];
    a0 += wgt * t0;
    a1 += wgt * t1;
  }
  // relu + LN stats
  float v[8];
#pragma unroll
  for (int j = 0; j < 4; ++j) { v[j] = fmaxf(a0[j], 0.f); v[4 + j] = fmaxf(a1[j], 0.f); }
  float s1 = 0.f, s2 = 0.f;
#pragma unroll
  for (int j = 0; j < 8; ++j) { s1 += v[j]; s2 += v[j] * v[j]; }
#pragma unroll
  for (int off = 32; off > 0; off >>= 1) {
    s1 += __shfl_xor(s1, off);
    s2 += __shfl_xor(s2, off);
  }
  const float invD = 1.0f / (float)HID;
  float mean = s1 * invD;
  float var = s2 * invD - mean * mean;
  float inv = rsqrtf(var + LN_EPS);
  bf16_t ob[8];
#pragma unroll
  for (int j = 0; j < 8; ++j) {
    int d = d0 + j;
    ob[j] = (bf16_t)((v[j] - mean) * inv * g[d] + b[d]);
  }
  *(bf16x8*)(out + (size_t)node * HID + d0) = *(bf16x8*)ob;
}

// one block per row. relu_first=1: y=LN(relu(x)); relu_first=0: y=relu(LN(x))
// input: fp32 inF. output: bf16 to outB if non-null, else fp32 to outF.
__global__ __launch_bounds__(256) void k_relu_ln(
    const float* __restrict__ inF, bf16_t* __restrict__ outB,
    float* __restrict__ outF, const float* __restrict__ g,
    const float* __restrict__ b, int D, int relu_first) {
  int row = blockIdx.x, tid = threadIdx.x;
  size_t base = (size_t)row * D;
  int per = D >> 8;  // 2 or 4
  float v[4];
  float s1 = 0.f, s2 = 0.f;
#pragma unroll
  for (int i = 0; i < 4; ++i) {
    if (i < per) {
      int d = tid + (i << 8);
      float x = inF[base + d];
      if (relu_first) x = fmaxf(x, 0.f);
      v[i] = x;
      s1 += x;
      s2 += x * x;
    }
  }
#pragma unroll
  for (int off = 32; off > 0; off >>= 1) {
    s1 += __shfl_xor(s1, off);
    s2 += __shfl_xor(s2, off);
  }
  __shared__ float ls1[4], ls2[4];
  int w = tid >> 6;
  if ((tid & 63) == 0) { ls1[w] = s1; ls2[w] = s2; }
  __syncthreads();
  float t1 = ls1[0] + ls1[1] + ls1[2] + ls1[3];
  float t2 = ls2[0] + ls2[1] + ls2[2] + ls2[3];
  float invD = 1.0f / (float)D;
  float mean = t1 * invD;
  float var = t2 * invD - mean * mean;
  float inv = rsqrtf(var + LN_EPS);
#pragma unroll
  for (int i = 0; i < 4; ++i) {
    if (i < per) {
      int d = tid + (i << 8);
      float y = (v[i] - mean) * inv * g[d] + b[d];
      if (!relu_first) y = fmaxf(y, 0.f);
      if (outB) outB[base + d] = (bf16_t)y;
      else outF[base + d] = y;
    }
  }
}

// ---------------- GEMM: C[M x N] = A[M x K] @ B[K x N] (+bias) ----------------
// Bt is B transposed: [N x K]. gather=1: A row m = concat(Hn[src[m]], Hn[dst[m]]).
// Output: fp32 to Cf.
#define BM 128
#define BN 128
#define BK 32
#define LDK 40  // 32 + 8 bf16 pad (keeps 16B alignment, breaks bank aliasing)

__global__ __launch_bounds__(256) void k_gemm(
    const bf16_t* __restrict__ A, const bf16_t* __restrict__ Hn,
    const int* __restrict__ srcI, const int* __restrict__ dstI,
    const bf16_t* __restrict__ Bt, const float* __restrict__ bias,
    float* __restrict__ Cf, int M, int N, int K, int gather) {
  __shared__ __align__(16) bf16_t sA[BM][LDK];
  __shared__ __align__(16) bf16_t sB[BN][LDK];
  __shared__ int sSrc[BM], sDst[BM];

  int tid = threadIdx.x;
  int row0 = blockIdx.y * BM, col0 = blockIdx.x * BN;

  if (gather) {
    if (tid < BM) {
      sSrc[tid] = srcI[row0 + tid];
      sDst[tid] = dstI[row0 + tid];
    }
    __syncthreads();
  }

  int w = tid >> 6, lane = tid & 63;
  int quad = lane >> 4, l15 = lane & 15;
  int wr = (w >> 1) << 6, wc = (w & 1) << 6;

  f32x4 acc[4][4] = {};

  for (int k0 = 0; k0 < K; k0 += BK) {
#pragma unroll
    for (int h = 0; h < 2; ++h) {
      int c = tid + (h << 8);
      int r = c >> 2, seg = c & 3;
      int kk = k0 + (seg << 3);
      const bf16_t* pa;
      if (gather) {
        int node = (kk < HID) ? sSrc[r] : sDst[r];
        pa = Hn + (size_t)node * HID + (kk & (HID - 1));
      } else {
        int gr = row0 + r;
        if (gr >= M) gr = M - 1;  // clamp; rows >= M never stored
        pa = A + (size_t)gr * K + kk;
      }
      *(bf16x8*)&sA[r][seg << 3] = *(const bf16x8*)pa;
      const bf16_t* pb = Bt + (size_t)(col0 + r) * K + kk;
      *(bf16x8*)&sB[r][seg << 3] = *(const bf16x8*)pb;
    }
    __syncthreads();

    bf16x8 af[4], bfr[4];
#pragma unroll
    for (int i = 0; i < 4; ++i)
      af[i] = *(const bf16x8*)&sA[wr + (i << 4) + l15][quad << 3];
#pragma unroll
    for (int j = 0; j < 4; ++j)
      bfr[j] = *(const bf16x8*)&sB[wc + (j << 4) + l15][quad << 3];
#pragma unroll
    for (int i = 0; i < 4; ++i)
#pragma unroll
      for (int j = 0; j < 4; ++j)
        acc[i][j] = __builtin_amdgcn_mfma_f32_16x16x32_bf16(af[i], bfr[j], acc[i][j], 0, 0, 0);
    __syncthreads();
  }

  // epilogue: C/D layout col=lane&15, row=quad*4+reg (verified m89/m91)
#pragma unroll
  for (int i = 0; i < 4; ++i) {
    int r0 = row0 + wr + (i << 4) + (quad << 2);
#pragma unroll
    for (int j = 0; j < 4; ++j) {
      int gc = col0 + wc + (j << 4) + l15;
      float bb = bias ? bias[gc] : 0.0f;
#pragma unroll
      for (int r2 = 0; r2 < 4; ++r2) {
        int gr = r0 + r2;
        if (gr < M) Cf[(size_t)gr * N + gc] = acc[i][j][r2] + bb;
      }
    }
  }
}

// out[e] = dot(z1[e,:512], mw2) + mb2 — one wave per edge, all fp32
__global__ __launch_bounds__(256) void k_gemv_out(
    const float* __restrict__ z1, const float* __restrict__ mw2,
    const float* __restrict__ mb2, float* __restrict__ out, int E) {
  int w = threadIdx.x >> 6, lane = threadIdx.x & 63;
  int e = blockIdx.x * 4 + w;
  if (e >= E) return;
  const float* zp = z1 + (size_t)e * HID + (lane << 3);
  float s = 0.f;
#pragma unroll
  for (int i = 0; i < 8; ++i) s += zp[i] * mw2[(lane << 3) + i];
#pragma unroll
  for (int off = 32; off > 0; off >>= 1) s += __shfl_xor(s, off);
  if (lane == 0) out[e] = s + mb2[0];
}

// ---------------- host launch ----------------

extern "C" void kernel_launch(void* const* d_in, const int* in_sizes, int n_in,
                              void* d_out, int out_size, void* d_ws, size_t ws_size,
                              hipStream_t stream) {
  const float* x = (const float*)d_in[0];
  const int* ei = (const int*)d_in[1];  // int64 in reference -> int32 from harness
  const float* w0 = (const float*)d_in[2];
  const float* b0 = (const float*)d_in[3];
  const float* wsL = (const float*)d_in[4];
  const float* bsL = (const float*)d_in[5];
  const float* ln_g = (const float*)d_in[6];
  const float* ln_b = (const float*)d_in[7];
  const float* mw0 = (const float*)d_in[8];
  const float* mb0 = (const float*)d_in[9];
  const float* mg0 = (const float*)d_in[10];
  const float* mbt0 = (const float*)d_in[11];
  const float* mw1 = (const float*)d_in[12];
  const float* mb1 = (const float*)d_in[13];
  const float* mg1 = (const float*)d_in[14];
  const float* mbt1 = (const float*)d_in[15];
  const float* mw2 = (const float*)d_in[16];
  const float* mb2 = (const float*)d_in[17];
  float* out = (float*)d_out;

  char* p = (char*)d_ws;
  auto alloc = [&](size_t bytes) -> void* {
    void* r = (void*)p;
    p += (bytes + 255) & ~(size_t)255;
    return r;
  };
  // persistent-through-MLP allocations first
  float* deg = (float*)alloc((size_t)N_NODES * 4);
  float* dis = (float*)alloc((size_t)N_NODES * 4);
  int* cnt = (int*)alloc((size_t)N_NODES * 4);
  int* cursor = (int*)alloc((size_t)N_NODES * 4);
  int* rowptr = (int*)alloc((size_t)(N_NODES + 1) * 4);
  int* esrc = (int*)alloc((size_t)N_EDGES * 4);
  float* ew = (float*)alloc((size_t)N_EDGES * 4);
  bf16_t* xb = (bf16_t*)alloc((size_t)N_NODES * IN_DIM * 2);
  bf16_t* hb0 = (bf16_t*)alloc((size_t)N_NODES * HID * 2);
  bf16_t* hb1 = (bf16_t*)alloc((size_t)N_NODES * HID * 2);
  bf16_t* w0t = (bf16_t*)alloc((size_t)HID * IN_DIM * 2);
  bf16_t* wst = (bf16_t*)alloc((size_t)3 * HID * HID * 2);
  bf16_t* mw0t = (bf16_t*)alloc((size_t)1024 * 1024 * 2);
  bf16_t* mw1t = (bf16_t*)alloc((size_t)512 * 1024 * 2);
  size_t fixed = (size_t)(p - (char*)d_ws);

  // GCN-phase T buffer; MLP chunk buffers alias the same region after GCN.
  char* pool = p;
  float* T = (float*)alloc((size_t)N_NODES * HID * 4);

  // per-edge MLP bytes: z0f 4096 + z0b 2048 + z1f 2048 = 8192
  int CE = 3200;
  const int ce_opts[3] = {32000, 16000, 6400};
  for (int i = 0; i < 3; ++i) {
    size_t need = fixed + (size_t)ce_opts[i] * 8192 + 1024;
    if (need <= ws_size) { CE = ce_opts[i]; break; }
  }
  char* q = pool;
  auto alloc2 = [&](size_t bytes) -> void* {
    void* r = (void*)q;
    q += (bytes + 255) & ~(size_t)255;
    return r;
  };
  float* z0f = (float*)alloc2((size_t)CE * 1024 * 4);
  bf16_t* z0b = (bf16_t*)alloc2((size_t)CE * 1024 * 2);
  float* z1f = (float*)alloc2((size_t)CE * 512 * 4);
  // NOTE: z0f overlaps T — T is consumed before the MLP writes z0f (the last
  // k_agg_ln of layer 3 reads T, then the MLP starts). Safe because stream-ordered.

  // ---- precompute: bf16 casts + transposed weights, degree norm, CSR ----
  k_cast<<<(N_NODES * IN_DIM + 255) / 256, 256, 0, stream>>>(x, xb, N_NODES * IN_DIM);
  k_tcast<<<(IN_DIM * HID + 255) / 256, 256, 0, stream>>>(w0, w0t, 7, HID, IN_DIM * HID);
  for (int i = 0; i < 3; ++i)
    k_tcast<<<(HID * HID + 255) / 256, 256, 0, stream>>>(
        wsL + (size_t)i * HID * HID, wst + (size_t)i * HID * HID, 9, HID, HID * HID);
  k_tcast<<<(1024 * 1024 + 255) / 256, 256, 0, stream>>>(mw0, mw0t, 10, 1024, 1024 * 1024);
  k_tcast<<<(1024 * 512 + 255) / 256, 256, 0, stream>>>(mw1, mw1t, 10, 512, 1024 * 512);

  k_deg_init<<<(N_NODES + 255) / 256, 256, 0, stream>>>(deg);
  k_deg_count<<<(N_EDGES + 255) / 256, 256, 0, stream>>>(ei + N_EDGES, deg);
  k_dis<<<(N_NODES + 255) / 256, 256, 0, stream>>>(deg, dis);

  k_zero2<<<(N_NODES + 255) / 256, 256, 0, stream>>>(cnt, cursor);
  k_cnt<<<(N_EDGES + 255) / 256, 256, 0, stream>>>(ei + N_EDGES, cnt);
  k_scan<<<1, 256, 0, stream>>>(cnt, rowptr);
  k_fill<<<(N_EDGES + 255) / 256, 256, 0, stream>>>(ei, dis, rowptr, cursor, esrc, ew);

  // ---- 4 GCN layers ----
  bf16_t* hbufs[2] = {hb0, hb1};
  for (int L = 0; L < 4; ++L) {
    const bf16_t* Ain = (L == 0) ? xb : hbufs[(L + 1) & 1];
    int K = (L == 0) ? IN_DIM : HID;
    const bf16_t* Bt = (L == 0) ? w0t : wst + (size_t)(L - 1) * HID * HID;
    dim3 grid(HID / BN, (N_NODES + BM - 1) / BM);
    k_gemm<<<grid, 256, 0, stream>>>(Ain, nullptr, nullptr, nullptr, Bt, nullptr,
                                     T, N_NODES, HID, K, 0);
    const float* bias = (L == 0) ? b0 : bsL + (size_t)(L - 1) * HID;
    k_agg_ln<<<(N_NODES + 3) / 4, 256, 0, stream>>>(
        T, rowptr, esrc, ew, dis, bias, ln_g + (size_t)L * HID,
        ln_b + (size_t)L * HID, hbufs[L & 1]);
  }
  bf16_t* hfin = hbufs[1];  // layer 3 writes hbufs[1]

  // ---- edge MLP, chunked ----
  int nchunks = N_EDGES / CE;
  for (int c = 0; c < nchunks; ++c) {
    int e0 = c * CE;
    const int* srcI = ei + e0;
    const int* dstI = ei + N_EDGES + e0;
    dim3 g1(1024 / BN, CE / BM);
    k_gemm<<<g1, 256, 0, stream>>>(nullptr, hfin, srcI, dstI, mw0t, mb0,
                                   z0f, CE, 1024, 1024, 1);
    k_relu_ln<<<CE, 256, 0, stream>>>(z0f, z0b, nullptr, mg0, mbt0, 1024, 0);
    dim3 g2(HID / BN, CE / BM);
    k_gemm<<<g2, 256, 0, stream>>>(z0b, nullptr, nullptr, nullptr, mw1t, mb1,
                                   z1f, CE, HID, 1024, 0);
    k_relu_ln<<<CE, 256, 0, stream>>>(z1f, nullptr, z1f, mg1, mbt1, HID, 0);
    k_gemv_out<<<CE / 4, 256, 0, stream>>>(z1f, mw2, mb2, out + e0, CE);
  }
  (void)in_sizes; (void)n_in; (void)out_size;
}

// Round 4
// 1430.233 us; speedup vs baseline: 2.2555x; 1.6343x over previous
//
#include <hip/hip_runtime.h>
#include <hip/hip_bf16.h>
#include <stdint.h>

typedef __bf16 bf16_t;
typedef bf16_t bf16x8 __attribute__((ext_vector_type(8)));
typedef float f32x4 __attribute__((ext_vector_type(4)));

#define N_NODES 10000
#define N_EDGES 160000
#define IN_DIM 128
#define HID 512
#define LN_EPS 1e-5f

#define AS1 __attribute__((address_space(1)))
#define AS3 __attribute__((address_space(3)))

static __device__ __forceinline__ void gload_lds16(const void* g, void* l) {
  __builtin_amdgcn_global_load_lds((const AS1 void*)g, (AS3 void*)l, 16, 0, 0);
}

// ---------------- small utility kernels ----------------

__global__ void k_cast(const float* __restrict__ s, bf16_t* __restrict__ d, int n) {
  int i = blockIdx.x * 256 + threadIdx.x;
  if (i < n) d[i] = (bf16_t)s[i];
}

// LDS-tiled transpose+cast: dst[N][K] = bf16(src[K][N]); grid (N/32, K/32), 256 thr
__global__ __launch_bounds__(256) void k_tpose(const float* __restrict__ src,
                                               bf16_t* __restrict__ dst, int K, int N) {
  __shared__ float t[32][33];
  int cx = threadIdx.x & 31, ry = threadIdx.x >> 5;  // 0..31, 0..7
  int n0 = blockIdx.x * 32, k0 = blockIdx.y * 32;
#pragma unroll
  for (int i = 0; i < 32; i += 8)
    t[ry + i][cx] = src[(size_t)(k0 + ry + i) * N + n0 + cx];
  __syncthreads();
#pragma unroll
  for (int i = 0; i < 32; i += 8)
    dst[(size_t)(n0 + ry + i) * K + k0 + cx] = (bf16_t)t[cx][ry + i];
}

__global__ void k_deg_init(float* deg) {
  int i = blockIdx.x * 256 + threadIdx.x;
  if (i < N_NODES) deg[i] = 1.0f;  // self-loop
}
__global__ void k_deg_count(const int* __restrict__ col, float* deg) {
  int e = blockIdx.x * 256 + threadIdx.x;
  if (e < N_EDGES) atomicAdd(&deg[col[e]], 1.0f);
}
__global__ void k_dis(const float* __restrict__ deg, float* __restrict__ dis) {
  int i = blockIdx.x * 256 + threadIdx.x;
  if (i < N_NODES) dis[i] = rsqrtf(deg[i]);  // deg >= 1 always
}

// ---------------- CSR build (edges sorted by target) ----------------

__global__ void k_zero2(int* a, int* b) {
  int i = blockIdx.x * 256 + threadIdx.x;
  if (i < N_NODES) { a[i] = 0; b[i] = 0; }
}
__global__ void k_cnt(const int* __restrict__ col, int* cnt) {
  int e = blockIdx.x * 256 + threadIdx.x;
  if (e < N_EDGES) atomicAdd(&cnt[col[e]], 1);
}
// single-block exclusive scan: rowptr[0..N_NODES]
__global__ __launch_bounds__(256) void k_scan(const int* __restrict__ cnt,
                                              int* __restrict__ rowptr) {
  __shared__ int part[256];
  __shared__ int pref[257];
  int tid = threadIdx.x;
  const int CH = 40;  // 256*40 >= 10001
  int s = 0;
  for (int i = 0; i < CH; ++i) {
    int idx = tid * CH + i;
    if (idx < N_NODES) s += cnt[idx];
  }
  part[tid] = s;
  __syncthreads();
  if (tid == 0) {
    int a = 0;
    for (int i = 0; i < 256; ++i) { pref[i] = a; a += part[i]; }
    pref[256] = a;
  }
  __syncthreads();
  int a = pref[tid];
  for (int i = 0; i < CH; ++i) {
    int idx = tid * CH + i;
    if (idx < N_NODES) {
      rowptr[idx] = a;
      a += cnt[idx];
    } else if (idx == N_NODES) {
      rowptr[idx] = a;
    }
  }
}
__global__ void k_fill(const int* __restrict__ ei, const float* __restrict__ dis,
                       const int* __restrict__ rowptr, int* __restrict__ cursor,
                       int* __restrict__ esrc, float* __restrict__ ew) {
  int e = blockIdx.x * 256 + threadIdx.x;
  if (e >= N_EDGES) return;
  int s = ei[e];
  int t = ei[N_EDGES + e];
  int pos = atomicAdd(&cursor[t], 1);
  int o = rowptr[t] + pos;
  esrc[o] = s;
  ew[o] = dis[s] * dis[t];
}

// ---------------- fused aggregation + ReLU + LayerNorm (T in bf16) ----------------
__global__ __launch_bounds__(256) void k_agg_ln(
    const bf16_t* __restrict__ T, const int* __restrict__ rowptr,
    const int* __restrict__ esrc, const float* __restrict__ ew,
    const float* __restrict__ dis, const float* __restrict__ bias,
    const float* __restrict__ g, const float* __restrict__ b,
    bf16_t* __restrict__ out) {
  int w = threadIdx.x >> 6, lane = threadIdx.x & 63;
  int node = blockIdx.x * 4 + w;
  if (node >= N_NODES) return;
  int d0 = lane << 3;  // 8 dims per lane
  float dw = dis[node];
  dw *= dw;
  float a[8];
  {
    bf16x8 tn = *(const bf16x8*)(T + (size_t)node * HID + d0);
    const f32x4* bi = (const f32x4*)(bias + d0);
    f32x4 bv0 = bi[0], bv1 = bi[1];
#pragma unroll
    for (int j = 0; j < 4; ++j) a[j] = dw * (float)tn[j] + bv0[j];
#pragma unroll
    for (int j = 0; j < 4; ++j) a[4 + j] = dw * (float)tn[4 + j] + bv1[j];
  }
  int e = rowptr[node], e1 = rowptr[node + 1];
  for (; e + 1 < e1; e += 2) {
    int s0 = esrc[e], s1i = esrc[e + 1];
    float w0 = ew[e], w1 = ew[e + 1];
    bf16x8 t0 = *(const bf16x8*)(T + (size_t)s0 * HID + d0);
    bf16x8 t1 = *(const bf16x8*)(T + (size_t)s1i * HID + d0);
#pragma unroll
    for (int j = 0; j < 8; ++j) a[j] += w0 * (float)t0[j] + w1 * (float)t1[j];
  }
  if (e < e1) {
    int s0 = esrc[e];
    float w0 = ew[e];
    bf16x8 t0 = *(const bf16x8*)(T + (size_t)s0 * HID + d0);
#pragma unroll
    for (int j = 0; j < 8; ++j) a[j] += w0 * (float)t0[j];
  }
  float s1 = 0.f, s2 = 0.f;
#pragma unroll
  for (int j = 0; j < 8; ++j) {
    a[j] = fmaxf(a[j], 0.f);
    s1 += a[j];
    s2 += a[j] * a[j];
  }
#pragma unroll
  for (int off = 32; off > 0; off >>= 1) {
    s1 += __shfl_xor(s1, off);
    s2 += __shfl_xor(s2, off);
  }
  const float invD = 1.0f / (float)HID;
  float mean = s1 * invD;
  float var = s2 * invD - mean * mean;
  float inv = rsqrtf(var + LN_EPS);
  bf16_t ob[8];
#pragma unroll
  for (int j = 0; j < 8; ++j) {
    int d = d0 + j;
    ob[j] = (bf16_t)((a[j] - mean) * inv * g[d] + b[d]);
  }
  *(bf16x8*)(out + (size_t)node * HID + d0) = *(bf16x8*)ob;
}

// wave-per-row: z = relu(LN(z)) in place, D=1024, bf16
__global__ __launch_bounds__(256) void k_ln_relu_1024(
    bf16_t* __restrict__ z, const float* __restrict__ g,
    const float* __restrict__ b, int rows) {
  int w = threadIdx.x >> 6, lane = threadIdx.x & 63;
  int row = blockIdx.x * 4 + w;
  if (row >= rows) return;
  bf16_t* zp = z + (size_t)row * 1024 + (lane << 4);  // 16 elems/lane
  bf16x8 v0 = *(bf16x8*)zp;
  bf16x8 v1 = *(bf16x8*)(zp + 8);
  float f[16];
#pragma unroll
  for (int j = 0; j < 8; ++j) { f[j] = (float)v0[j]; f[8 + j] = (float)v1[j]; }
  float s1 = 0.f, s2 = 0.f;
#pragma unroll
  for (int j = 0; j < 16; ++j) { s1 += f[j]; s2 += f[j] * f[j]; }
#pragma unroll
  for (int off = 32; off > 0; off >>= 1) {
    s1 += __shfl_xor(s1, off);
    s2 += __shfl_xor(s2, off);
  }
  const float invD = 1.0f / 1024.0f;
  float mean = s1 * invD;
  float var = s2 * invD - mean * mean;
  float inv = rsqrtf(var + LN_EPS);
  int d0 = lane << 4;
  bf16_t o0[8], o1[8];
#pragma unroll
  for (int j = 0; j < 8; ++j) {
    o0[j] = (bf16_t)fmaxf((f[j] - mean) * inv * g[d0 + j] + b[d0 + j], 0.f);
    o1[j] = (bf16_t)fmaxf((f[8 + j] - mean) * inv * g[d0 + 8 + j] + b[d0 + 8 + j], 0.f);
  }
  *(bf16x8*)zp = *(bf16x8*)o0;
  *(bf16x8*)(zp + 8) = *(bf16x8*)o1;
}

// wave-per-row: out[row] = dot(relu(LN(z1[row])), mw2) + mb2, D=512, bf16 in
__global__ __launch_bounds__(256) void k_ln_dot(
    const bf16_t* __restrict__ z1, const float* __restrict__ g,
    const float* __restrict__ b, const float* __restrict__ mw2,
    const float* __restrict__ mb2, float* __restrict__ out, int rows) {
  int w = threadIdx.x >> 6, lane = threadIdx.x & 63;
  int row = blockIdx.x * 4 + w;
  if (row >= rows) return;
  int d0 = lane << 3;
  bf16x8 v = *(const bf16x8*)(z1 + (size_t)row * 512 + d0);
  float f[8];
#pragma unroll
  for (int j = 0; j < 8; ++j) f[j] = (float)v[j];
  float s1 = 0.f, s2 = 0.f;
#pragma unroll
  for (int j = 0; j < 8; ++j) { s1 += f[j]; s2 += f[j] * f[j]; }
#pragma unroll
  for (int off = 32; off > 0; off >>= 1) {
    s1 += __shfl_xor(s1, off);
    s2 += __shfl_xor(s2, off);
  }
  const float invD = 1.0f / 512.0f;
  float mean = s1 * invD;
  float var = s2 * invD - mean * mean;
  float inv = rsqrtf(var + LN_EPS);
  float acc = 0.f;
#pragma unroll
  for (int j = 0; j < 8; ++j) {
    float y = fmaxf((f[j] - mean) * inv * g[d0 + j] + b[d0 + j], 0.f);
    acc += y * mw2[d0 + j];
  }
#pragma unroll
  for (int off = 32; off > 0; off >>= 1) acc += __shfl_xor(acc, off);
  if (lane == 0) out[row] = acc + mb2[0];
}

// ---------------- GEMM (m97 structure) ----------------
#define BM 128
#define BN 128
#define BK 32

__global__ __launch_bounds__(256) void k_gemm(
    const bf16_t* __restrict__ A, const bf16_t* __restrict__ Hn,
    const int* __restrict__ srcI, const int* __restrict__ dstI,
    const bf16_t* __restrict__ Bt, const float* __restrict__ bias,
    bf16_t* __restrict__ C, int M, int N, int K, int gather) {
  __shared__ __align__(16) bf16_t sA[BM * BK];
  __shared__ __align__(16) bf16_t sB[BN * BK];

  int tid = threadIdx.x;
  int row0 = blockIdx.y * BM, col0 = blockIdx.x * BN;
  int lane = tid & 63, w = tid >> 6;
  int quad = lane >> 4, l15 = lane & 15;
  int wr = (w >> 1) << 6, wc = (w & 1) << 6;
  int qoff = quad << 3;

  int r0l = tid >> 2, r1l = r0l + 64;  // tile rows staged by this thread
  int kseg = (tid & 3) << 3;           // 8-bf16 k-segment

  const bf16_t *pa0 = nullptr, *pa1 = nullptr;
  int aS0 = 0, aD0 = 0, aS1 = 0, aD1 = 0;
  if (gather) {
    aS0 = srcI[row0 + r0l]; aD0 = dstI[row0 + r0l];
    aS1 = srcI[row0 + r1l]; aD1 = dstI[row0 + r1l];
  } else {
    int g0 = row0 + r0l; if (g0 >= M) g0 = M - 1;  // clamp; never stored
    int g1 = row0 + r1l; if (g1 >= M) g1 = M - 1;
    pa0 = A + (size_t)g0 * K;
    pa1 = A + (size_t)g1 * K;
  }
  const bf16_t* pb0 = Bt + (size_t)(col0 + r0l) * K;
  const bf16_t* pb1 = Bt + (size_t)(col0 + r1l) * K;

  int ldsb = (tid & ~63) * 8;  // wave-uniform LDS element base (c_base*8)

  f32x4 acc[4][4] = {};

  for (int k0 = 0; k0 < K; k0 += BK) {
    int kk = k0 + kseg;
    const bf16_t *ga0, *ga1;
    if (gather) {
      int off = kk & (HID - 1);
      ga0 = Hn + (size_t)(kk < HID ? aS0 : aD0) * HID + off;
      ga1 = Hn + (size_t)(kk < HID ? aS1 : aD1) * HID + off;
    } else {
      ga0 = pa0 + kk;
      ga1 = pa1 + kk;
    }
    gload_lds16(ga0, sA + ldsb);
    gload_lds16(ga1, sA + ldsb + 2048);
    gload_lds16(pb0 + kk, sB + ldsb);
    gload_lds16(pb1 + kk, sB + ldsb + 2048);
    __syncthreads();

    bf16x8 af[4], bfr[4];
#pragma unroll
    for (int i = 0; i < 4; ++i)
      af[i] = *(const bf16x8*)&sA[(wr + (i << 4) + l15) * BK + qoff];
#pragma unroll
    for (int j = 0; j < 4; ++j)
      bfr[j] = *(const bf16x8*)&sB[(wc + (j << 4) + l15) * BK + qoff];
#pragma unroll
    for (int i = 0; i < 4; ++i)
#pragma unroll
      for (int j = 0; j < 4; ++j)
        acc[i][j] = __builtin_amdgcn_mfma_f32_16x16x32_bf16(af[i], bfr[j], acc[i][j], 0, 0, 0);
    __syncthreads();
  }

#pragma unroll
  for (int i = 0; i < 4; ++i) {
    int r0e = row0 + wr + (i << 4) + (quad << 2);
#pragma unroll
    for (int j = 0; j < 4; ++j) {
      int gc = col0 + wc + (j << 4) + l15;
      float bb = bias ? bias[gc] : 0.0f;
#pragma unroll
      for (int r2 = 0; r2 < 4; ++r2) {
        int gr = r0e + r2;
        if (gr < M) C[(size_t)gr * N + gc] = (bf16_t)(acc[i][j][r2] + bb);
      }
    }
  }
}

// ---------------- host launch ----------------

extern "C" void kernel_launch(void* const* d_in, const int* in_sizes, int n_in,
                              void* d_out, int out_size, void* d_ws, size_t ws_size,
                              hipStream_t stream) {
  const float* x = (const float*)d_in[0];
  const int* ei = (const int*)d_in[1];
  const float* w0 = (const float*)d_in[2];
  const float* b0 = (const float*)d_in[3];
  const float* wsL = (const float*)d_in[4];
  const float* bsL = (const float*)d_in[5];
  const float* ln_g = (const float*)d_in[6];
  const float* ln_b = (const float*)d_in[7];
  const float* mw0 = (const float*)d_in[8];
  const float* mb0 = (const float*)d_in[9];
  const float* mg0 = (const float*)d_in[10];
  const float* mbt0 = (const float*)d_in[11];
  const float* mw1 = (const float*)d_in[12];
  const float* mb1 = (const float*)d_in[13];
  const float* mg1 = (const float*)d_in[14];
  const float* mbt1 = (const float*)d_in[15];
  const float* mw2 = (const float*)d_in[16];
  const float* mb2 = (const float*)d_in[17];
  float* out = (float*)d_out;

  char* p = (char*)d_ws;
  auto alloc = [&](size_t bytes) -> void* {
    void* r = (void*)p;
    p += (bytes + 255) & ~(size_t)255;
    return r;
  };
  float* deg = (float*)alloc((size_t)N_NODES * 4);
  float* dis = (float*)alloc((size_t)N_NODES * 4);
  int* cnt = (int*)alloc((size_t)N_NODES * 4);
  int* cursor = (int*)alloc((size_t)N_NODES * 4);
  int* rowptr = (int*)alloc((size_t)(N_NODES + 1) * 4);
  int* esrc = (int*)alloc((size_t)N_EDGES * 4);
  float* ew = (float*)alloc((size_t)N_EDGES * 4);
  bf16_t* xb = (bf16_t*)alloc((size_t)N_NODES * IN_DIM * 2);
  bf16_t* hb0 = (bf16_t*)alloc((size_t)N_NODES * HID * 2);
  bf16_t* hb1 = (bf16_t*)alloc((size_t)N_NODES * HID * 2);
  bf16_t* w0t = (bf16_t*)alloc((size_t)HID * IN_DIM * 2);
  bf16_t* wst = (bf16_t*)alloc((size_t)3 * HID * HID * 2);
  bf16_t* mw0t = (bf16_t*)alloc((size_t)1024 * 1024 * 2);
  bf16_t* mw1t = (bf16_t*)alloc((size_t)512 * 1024 * 2);
  size_t fixed = (size_t)(p - (char*)d_ws);

  // overlap pool: GCN-phase T (bf16) vs MLP z0 (2048 B/edge) + z1 (1024 B/edge)
  int CE = 3200;
  const int ce_opts[4] = {160000, 80000, 32000, 16000};
  for (int i = 0; i < 4; ++i) {
    size_t pool_need = (size_t)ce_opts[i] * 3072;
    size_t tneed = (size_t)N_NODES * HID * 2;
    if (pool_need < tneed) pool_need = tneed;
    if (fixed + pool_need + 4096 <= ws_size) { CE = ce_opts[i]; break; }
  }
  char* pool = p;
  bf16_t* T = (bf16_t*)pool;
  bf16_t* z0 = (bf16_t*)pool;  // aliases T; GCN fully precedes MLP (same stream)
  bf16_t* z1 = (bf16_t*)(pool + (size_t)CE * 2048);

  k_cast<<<(N_NODES * IN_DIM + 255) / 256, 256, 0, stream>>>(x, xb, N_NODES * IN_DIM);
  { dim3 g(HID / 32, IN_DIM / 32);
    k_tpose<<<g, 256, 0, stream>>>(w0, w0t, IN_DIM, HID); }
  for (int i = 0; i < 3; ++i) {
    dim3 g(HID / 32, HID / 32);
    k_tpose<<<g, 256, 0, stream>>>(wsL + (size_t)i * HID * HID,
                                   wst + (size_t)i * HID * HID, HID, HID);
  }
  { dim3 g(1024 / 32, 1024 / 32);
    k_tpose<<<g, 256, 0, stream>>>(mw0, mw0t, 1024, 1024); }
  { dim3 g(512 / 32, 1024 / 32);
    k_tpose<<<g, 256, 0, stream>>>(mw1, mw1t, 1024, 512); }

  k_deg_init<<<(N_NODES + 255) / 256, 256, 0, stream>>>(deg);
  k_deg_count<<<(N_EDGES + 255) / 256, 256, 0, stream>>>(ei + N_EDGES, deg);
  k_dis<<<(N_NODES + 255) / 256, 256, 0, stream>>>(deg, dis);

  k_zero2<<<(N_NODES + 255) / 256, 256, 0, stream>>>(cnt, cursor);
  k_cnt<<<(N_EDGES + 255) / 256, 256, 0, stream>>>(ei + N_EDGES, cnt);
  k_scan<<<1, 256, 0, stream>>>(cnt, rowptr);
  k_fill<<<(N_EDGES + 255) / 256, 256, 0, stream>>>(ei, dis, rowptr, cursor, esrc, ew);

  bf16_t* hbufs[2] = {hb0, hb1};
  for (int L = 0; L < 4; ++L) {
    const bf16_t* Ain = (L == 0) ? xb : hbufs[(L + 1) & 1];
    int K = (L == 0) ? IN_DIM : HID;
    const bf16_t* Bt = (L == 0) ? w0t : wst + (size_t)(L - 1) * HID * HID;
    dim3 grid(HID / BN, (N_NODES + BM - 1) / BM);
    k_gemm<<<grid, 256, 0, stream>>>(Ain, nullptr, nullptr, nullptr, Bt, nullptr,
                                     T, N_NODES, HID, K, 0);
    const float* bias = (L == 0) ? b0 : bsL + (size_t)(L - 1) * HID;
    k_agg_ln<<<(N_NODES + 3) / 4, 256, 0, stream>>>(
        T, rowptr, esrc, ew, dis, bias, ln_g + (size_t)L * HID,
        ln_b + (size_t)L * HID, hbufs[L & 1]);
  }
  bf16_t* hfin = hbufs[1];

  int nchunks = N_EDGES / CE;
  for (int c = 0; c < nchunks; ++c) {
    int e0 = c * CE;
    const int* srcI = ei + e0;
    const int* dstI = ei + N_EDGES + e0;
    dim3 g1(1024 / BN, CE / BM);
    k_gemm<<<g1, 256, 0, stream>>>(nullptr, hfin, srcI, dstI, mw0t, mb0,
                                   z0, CE, 1024, 1024, 1);
    k_ln_relu_1024<<<CE / 4, 256, 0, stream>>>(z0, mg0, mbt0, CE);
    dim3 g2(HID / BN, CE / BM);
    k_gemm<<<g2, 256, 0, stream>>>(z0, nullptr, nullptr, nullptr, mw1t, mb1,
                                   z1, CE, HID, 1024, 0);
    k_ln_dot<<<CE / 4, 256, 0, stream>>>(z1, mg1, mbt1, mw2, mb2, out + e0, CE);
  }
  (void)in_sizes; (void)n_in; (void)out_size;
}